// Round 1
// 128.295 us; speedup vs baseline: 1.0060x; 1.0060x over previous
//
#include <hip/hip_runtime.h>

using bf16x8 = __attribute__((ext_vector_type(8))) short;
using f32x4  = __attribute__((ext_vector_type(4))) float;
typedef unsigned short u16;
typedef __attribute__((ext_vector_type(8))) unsigned short u16x8;
typedef __attribute__((ext_vector_type(4))) unsigned short u16x4;

__device__ __forceinline__ u16 f2b(float f){
  unsigned int i=__float_as_uint(f);
  return (u16)((i + 0x7FFFu + ((i>>16)&1u))>>16);
}
__device__ __forceinline__ float b2f(u16 u){
  union{unsigned int i; float f;}v; v.i=((unsigned int)u)<<16; return v.f;
}
__device__ __forceinline__ void async16(const void* g, void* l){
  __builtin_amdgcn_global_load_lds((__attribute__((address_space(1))) void*)(g),
                                   (__attribute__((address_space(3))) void*)(l), 16, 0, 0);
}
__device__ __forceinline__ float gelu_tanh(float v){
  float u = v*(0.7978845608f + 0.0356774081f*v*v);
  float e = __expf(-2.0f*fabsf(u));
  float th = (1.0f-e)/(1.0f+e);
  th = (u<0.f)? -th : th;
  return 0.5f*v*(1.0f+th);
}

#define BARX() do{ __asm__ volatile("" ::: "memory"); \
                   __builtin_amdgcn_s_barrier(); \
                   __asm__ volatile("" ::: "memory"); }while(0)
#define WAITV(n) __asm__ volatile("s_waitcnt vmcnt(" #n ")" ::: "memory")
#define WAITL()  __asm__ volatile("s_waitcnt lgkmcnt(0)" ::: "memory")

// ---------- prep: fp32 weights -> bf16, PRE-SWIZZLED into LDS image order ----------
// Image: per 128x128 chunk, flat u16 index = (c*128 + n)*8 + e
//   n = output col within chunk, c = k-octet (k = c*8+e)
__global__ void prep_kernel(const float* __restrict__ wqkv, const float* __restrict__ wproj,
                            const float* __restrict__ wfc1, const float* __restrict__ wfc2,
                            u16* __restrict__ tqkv, u16* __restrict__ tproj,
                            u16* __restrict__ tfc1, u16* __restrict__ tfc2)
{
  int idx = blockIdx.x*256 + threadIdx.x;
  if (idx < 49152){
    int nc = idx>>14, r = idx&16383, i = r>>3, e = r&7, n = i&127, c = i>>7;
    tqkv[idx] = f2b(wqkv[(c*8+e)*384 + nc*128 + n]);
  } else if (idx < 65536){
    int r = idx-49152; int i=r>>3, e=r&7, n=i&127, c=i>>7;
    tproj[r] = f2b(wproj[(c*8+e)*128 + n]);
  } else if (idx < 131072){
    int t = idx-65536; int nc=t>>14, r=t&16383, i=r>>3, e=r&7, n=i&127, c=i>>7;
    tfc1[t] = f2b(wfc1[(c*8+e)*512 + nc*128 + n]);
  } else if (idx < 196608){
    int t = idx-131072; int nc=t>>14, r=t&16383, i=r>>3, e=r&7, n=i&127, c=i>>7;
    tfc2[t] = f2b(wfc2[(nc*128 + c*8 + e)*128 + n]);
  }
}

// aout layout: per 32-token tile, c-major chunks:
//   u16 index = ((tok>>5)*16 + (ch>>3))*256 + (tok&31)*8 + (ch&7)

// ---------- K2: LN1 + one QKV chunk GEMM. 32-token tile, grid (392, 3) ----------
__global__ __launch_bounds__(256)
void qkv_ln_kernel(const float* __restrict__ x,
                   const float* __restrict__ ln1w, const float* __restrict__ ln1b,
                   const u16* __restrict__ tqkv, const float* __restrict__ bqkv,
                   u16* __restrict__ qb, u16* __restrict__ kb, u16* __restrict__ vb)
{
  __shared__ __align__(16) char smem[40960];
  char* lA = smem;            // 32x128 bf16 c-major chunks (8 KB)
  char* lB = smem + 8192;     // 128x128 bf16 c-major chunks (32 KB)

  const int tid = threadIdx.x;
  const int lane = tid&63, wid = tid>>6;
  const int quad = lane>>4, lrow = lane&15;
  const int m0 = blockIdx.x*32;
  const int nc = blockIdx.y;
  const int wm = (wid&1)*16, wn = (wid>>1)*64;

  // ---- stage weight chunk (coalesced: global i*16 -> LDS i*16) ----
  #pragma unroll
  for (int kk=0;kk<8;kk++){
    int i = tid + kk*256;          // 2048 chunks
    async16(tqkv + (size_t)nc*16384 + i*8, lB + i*16);
  }

  // ---- LN1 in registers: thread = (row=tid>>3, g=tid&7), 16 channels ----
  {
    const int row = tid>>3, g = tid&7;
    float xv[16];
    const float4* xr = (const float4*)(x + (size_t)(m0+row)*128 + g*16);
    float s=0.f, sq=0.f;
    #pragma unroll
    for (int c4=0;c4<4;c4++){
      float4 t = xr[c4];
      xv[c4*4]=t.x; xv[c4*4+1]=t.y; xv[c4*4+2]=t.z; xv[c4*4+3]=t.w;
      s += t.x+t.y+t.z+t.w;
      sq += t.x*t.x+t.y*t.y+t.z*t.z+t.w*t.w;
    }
    s  += __shfl_xor(s,1);  s  += __shfl_xor(s,2);  s  += __shfl_xor(s,4);
    sq += __shfl_xor(sq,1); sq += __shfl_xor(sq,2); sq += __shfl_xor(sq,4);
    float mean = s*0.0078125f;
    float rstd = rsqrtf(sq*0.0078125f - mean*mean + 1e-5f);
    const float4* wr = (const float4*)(ln1w + g*16);
    const float4* br = (const float4*)(ln1b + g*16);
    u16 nv[16];
    #pragma unroll
    for (int c4=0;c4<4;c4++){
      float4 w4 = wr[c4], b4 = br[c4];
      nv[c4*4]   = f2b((xv[c4*4]  -mean)*rstd*w4.x + b4.x);
      nv[c4*4+1] = f2b((xv[c4*4+1]-mean)*rstd*w4.y + b4.y);
      nv[c4*4+2] = f2b((xv[c4*4+2]-mean)*rstd*w4.z + b4.z);
      nv[c4*4+3] = f2b((xv[c4*4+3]-mean)*rstd*w4.w + b4.w);
    }
    #pragma unroll
    for (int cc=0;cc<2;cc++){
      u16x8 pk;
      #pragma unroll
      for (int e=0;e<8;e++) pk[e] = nv[cc*8+e];
      *(u16x8*)(lA + (((g*2+cc)*32 + row)<<4)) = pk;
    }
  }
  __syncthreads();

  // ---- MFMA: wave = 16 rows x 64 cols ----
  f32x4 acc[4] = {};
  #pragma unroll
  for (int ks=0;ks<4;ks++){
    bf16x8 af = ((const bf16x8*)lA)[(ks*4+quad)*32 + wm + lrow];
    #pragma unroll
    for (int j=0;j<4;j++){
      bf16x8 bfr = ((const bf16x8*)lB)[(ks*4+quad)*128 + wn + j*16 + lrow];
      acc[j] = __builtin_amdgcn_mfma_f32_16x16x32_bf16(af, bfr, acc[j], 0,0,0);
    }
  }

  const float scale = 0.17677669529663687f;
  u16* dst = (nc==0)? qb : ((nc==1)? kb : vb);
  #pragma unroll
  for (int j=0;j<4;j++){
    int col = wn + j*16 + lrow;
    float bia = bqkv[nc*128 + col];
    #pragma unroll
    for (int r=0;r<4;r++){
      int row = m0 + wm + quad*4 + r;
      float val = acc[j][r] + bia;
      if (nc==0) val *= scale;
      dst[(size_t)row*128 + col] = f2b(val);
    }
  }
}

// ---------- K3: MFMA neighborhood attention ----------
#define KT_S 40
#define VT_S 232
#define P_S  152
__global__ __launch_bounds__(256)
void attn_kernel(const u16* __restrict__ qb, const u16* __restrict__ kb,
                 const u16* __restrict__ vb, const float* __restrict__ rpb,
                 u16* __restrict__ aout)
{
  __shared__ __align__(16) char smem[50192];
  u16*  kt   = (u16*)smem;
  u16*  vt   = (u16*)(smem + 15680);
  u16*  Pm   = (u16*)(smem + 30528);
  float* srpb= (float*)(smem + 49984);

  const int tid = threadIdx.x;
  const int tile = blockIdx.x, bh = blockIdx.y;
  const int b = bh>>2, h = bh&3;
  const int ty = (tile/7)*8, tx = (tile%7)*8;
  const int lane = tid&63, wid = tid>>6;
  const int quad = lane>>4, lrow = lane&15;

  #pragma unroll
  for (int kk=0;kk<4;kk++){
    int i = tid + kk*256;
    if (i < 784){
      int pos = i>>2, oct = i&3;
      int hy = pos/14, hx = pos - hy*14;
      int gy = ty + hy - 3, gx = tx + hx - 3;
      u16x8 kv = {0,0,0,0,0,0,0,0};
      if (gy>=0 && gy<56 && gx>=0 && gx<56)
        kv = *(const u16x8*)(kb + ((size_t)(b*3136 + gy*56 + gx)*128 + h*32 + oct*8));
      *(u16x8*)(kt + pos*KT_S + oct*8) = kv;
    }
  }
  #pragma unroll
  for (int kk=0;kk<4;kk++){
    int i = tid + kk*256;
    if (i < 896){
      int pos = i>>2, oct = i&3;
      u16x8 vv = {0,0,0,0,0,0,0,0};
      if (pos < 196){
        int hy = pos/14, hx = pos - hy*14;
        int gy = ty + hy - 3, gx = tx + hx - 3;
        if (gy>=0 && gy<56 && gx>=0 && gx<56)
          vv = *(const u16x8*)(vb + ((size_t)(b*3136 + gy*56 + gx)*128 + h*32 + oct*8));
      }
      #pragma unroll
      for (int j=0;j<8;j++) vt[(oct*8+j)*VT_S + pos] = vv[j];
    }
  }
  if (tid < 49) srpb[tid] = rpb[h*49 + tid];
  __syncthreads();

  const int pxq = wid*16 + lrow;
  const int tokq = b*3136 + (ty + (pxq>>3))*56 + tx + (pxq&7);
  bf16x8 qf = *(const bf16x8*)(qb + (size_t)tokq*128 + h*32 + quad*8);

  f32x4 sc[7];
  const f32x4 zf = {0.f,0.f,0.f,0.f};
  #pragma unroll
  for (int cg=0;cg<7;cg++){
    int pos = wid*28 + cg*16 + lrow;
    bf16x8 kf = *(const bf16x8*)(kt + pos*KT_S + quad*8);
    sc[cg] = __builtin_amdgcn_mfma_f32_16x16x32_bf16(qf, kf, zf, 0,0,0);
  }

  const int lyq = quad>>1;
  #pragma unroll
  for (int cg=0;cg<7;cg++){
    int np = cg*16 + lrow;
    int nh = np/14, hx = np - nh*14;
    int dy = nh - lyq;
    #pragma unroll
    for (int r=0;r<4;r++){
      int lx = (quad*4+r)&7;
      int dx = hx - lx;
      bool in = ((unsigned)dy<7u) && ((unsigned)dx<7u);
      float bias = srpb[in ? (dy*7+dx) : 0];
      sc[cg][r] = in ? (sc[cg][r] + bias) : -1e30f;
    }
  }
  float inv[4];
  #pragma unroll
  for (int r=0;r<4;r++){
    float m = sc[0][r];
    #pragma unroll
    for (int cg=1;cg<7;cg++) m = fmaxf(m, sc[cg][r]);
    m = fmaxf(m, __shfl_xor(m,1)); m = fmaxf(m, __shfl_xor(m,2));
    m = fmaxf(m, __shfl_xor(m,4)); m = fmaxf(m, __shfl_xor(m,8));
    float l = 0.f;
    #pragma unroll
    for (int cg=0;cg<7;cg++){ float p = __expf(sc[cg][r]-m); sc[cg][r]=p; l+=p; }
    l += __shfl_xor(l,1); l += __shfl_xor(l,2);
    l += __shfl_xor(l,4); l += __shfl_xor(l,8);
    inv[r]=1.f/l;
  }

  u16* Pw = Pm + wid*16*P_S;
  #pragma unroll
  for (int cg=0;cg<7;cg++){
    int np = cg*16 + lrow;
    #pragma unroll
    for (int r=0;r<4;r++)
      Pw[(quad*4+r)*P_S + np] = f2b(sc[cg][r]);
  }
  { int zr = lane>>2, seg = lane&3;
    u16x4 z4 = {0,0,0,0};
    *(u16x4*)(Pw + zr*P_S + 112 + seg*4) = z4; }
  __syncthreads();

  f32x4 oacc[2] = {zf, zf};
  #pragma unroll
  for (int ks=0;ks<4;ks++){
    bf16x8 pf = *(const bf16x8*)(Pw + lrow*P_S + ks*32 + quad*8);
    #pragma unroll
    for (int cg2=0;cg2<2;cg2++){
      bf16x8 vf = *(const bf16x8*)(vt + (cg2*16+lrow)*VT_S + wid*28 + ks*32 + quad*8);
      oacc[cg2] = __builtin_amdgcn_mfma_f32_16x16x32_bf16(pf, vf, oacc[cg2], 0,0,0);
    }
  }
  #pragma unroll
  for (int r=0;r<4;r++){
    int px = wid*16 + quad*4 + r;
    int tok = b*3136 + (ty + (px>>3))*56 + tx + (px&7);
    #pragma unroll
    for (int cg2=0;cg2<2;cg2++){
      int ch = h*32 + cg2*16 + lrow;
      aout[(size_t)((tok>>5)*16 + (ch>>3))*256 + (tok&31)*8 + (ch&7)]
        = f2b(oacc[cg2][r]*inv[r]);
    }
  }
}

// ---------- K4 v2: PROJ + residual + LN2 + FC1 + GELU + FC2 + residual ----------
// M=64 tokens/block (grid 196 -> ONE block-round, half the weight L2 traffic),
// 512 threads / 8 waves, 3-buffer counted-vmcnt weight pipeline (T3+T4):
// stage chunk k+2 while computing chunk k; never vmcnt(0) in the steady loop.
// LDS = 3x32KB B-bufs + 16KB A (aout->gelu; red aliases first 1KB) + 16KB xn2 = 128KB.

__device__ __forceinline__ void stage32k(const u16* __restrict__ src, char* dst, int tid){
  #pragma unroll
  for (int kk=0;kk<4;kk++){ int i = tid + kk*512; async16(src + (size_t)i*8, dst + i*16); }
}

// one wave-tile (16 rows x 64 cols) of a 64x128 = A(64x128 chunked) @ B(128x128 chunked)
__device__ __forceinline__ void mfma16(const char* Ab, const char* Bb,
                                       int quad, int lrow, int wm, int wn, f32x4 acc[4]){
  const int row = wm + lrow;
  #pragma unroll
  for (int ks=0;ks<4;ks++){
    bf16x8 af = ((const bf16x8*)Ab)[(row>>5)*512 + (ks*4+quad)*32 + (row&31)];
    #pragma unroll
    for (int j=0;j<4;j++){
      bf16x8 bfr = ((const bf16x8*)Bb)[(ks*4+quad)*128 + wn + j*16 + lrow];
      acc[j] = __builtin_amdgcn_mfma_f32_16x16x32_bf16(af, bfr, acc[j], 0,0,0);
    }
  }
}

__device__ __forceinline__ void fc1_phase(const char* xn2, const char* B, char* lA,
                                          const float* __restrict__ bfc1c,
                                          int quad, int lrow, int wm, int wn){
  f32x4 a2[4] = {};
  __builtin_amdgcn_s_setprio(1);
  mfma16(xn2, B, quad, lrow, wm, wn, a2);
  __builtin_amdgcn_s_setprio(0);
  #pragma unroll
  for (int j=0;j<4;j++){
    int col = wn + j*16 + lrow;
    float bia = bfc1c[col];
    #pragma unroll
    for (int r=0;r<4;r++){
      int row = wm + quad*4 + r;
      float g = gelu_tanh(a2[j][r] + bia);
      ((u16*)lA)[(row>>5)*4096 + ((col>>3)*32 + (row&31))*8 + (col&7)] = f2b(g);
    }
  }
}

__global__ __launch_bounds__(512)
void mega_mlp_kernel(const u16* __restrict__ aout, const float* __restrict__ x,
                     const u16* __restrict__ tproj, const float* __restrict__ bproj,
                     const float* __restrict__ ln2w, const float* __restrict__ ln2b,
                     const u16* __restrict__ tfc1, const float* __restrict__ bfc1,
                     const u16* __restrict__ tfc2, const float* __restrict__ bfc2,
                     float* __restrict__ out)
{
  __shared__ __align__(16) char smem[131072];
  char* B0  = smem;
  char* B1  = smem + 32768;
  char* B2  = smem + 65536;
  char* lA  = smem + 98304;          // 16KB: aout tile, then gelu buffer
  char* xn2 = smem + 114688;         // 16KB: LN2 output
  float* redS = (float*)lA;          // aliases lA[0:512]  (aout dead after P0)
  float* redQ = redS + 128;          // aliases lA[512:1024]

  const int tid = threadIdx.x;
  const int lane = tid&63, wid = tid>>6;
  const int quad = lane>>4, lrow = lane&15;
  const int m0 = blockIdx.x*64;
  const int wm = (wid&3)*16, wn = (wid>>2)*64;
  const int half = wid>>2;

  // ---- x residual loads FIRST (oldest vmem ops; done by prologue WAITV) ----
  float xv[4][4];
  #pragma unroll
  for (int j=0;j<4;j++){
    #pragma unroll
    for (int r=0;r<4;r++)
      xv[j][r] = x[(size_t)(m0+wm+quad*4+r)*128 + wn + j*16 + lrow];
  }

  // ---- prologue: S0 (proj), aout tile, S1 (fc1 c0), S2 (fc2 c0) ----
  stage32k(tproj, B0, tid);                          // 4 ops
  #pragma unroll
  for (int kk=0;kk<2;kk++){                          // 2 ops (aout 16KB)
    int i = tid + kk*512;
    async16(aout + (size_t)blockIdx.x*8192 + i*8, lA + i*16);
  }
  stage32k(tfc1,           B1, tid);                 // S1: 4 ops
  stage32k(tfc2,           B2, tid);                 // S2: 4 ops
  WAITV(8); BARX();                                  // x + S0 + aout done; S1,S2 in flight

  // ---- P0: proj ----
  f32x4 acc[4] = {};
  __builtin_amdgcn_s_setprio(1);
  mfma16(lA, B0, quad, lrow, wm, wn, acc);
  __builtin_amdgcn_s_setprio(0);
  float x1v[4][4]; float ps[4]={0,0,0,0}, pq[4]={0,0,0,0};
  #pragma unroll
  for (int j=0;j<4;j++){
    float bia = bproj[wn + j*16 + lrow];
    #pragma unroll
    for (int r=0;r<4;r++){
      float val = acc[j][r] + bia + xv[j][r];
      x1v[j][r] = val; ps[r]+=val; pq[r]+=val*val;
    }
  }
  #pragma unroll
  for (int r=0;r<4;r++){
    #pragma unroll
    for (int off=1; off<16; off<<=1){
      ps[r]+=__shfl_xor(ps[r],off); pq[r]+=__shfl_xor(pq[r],off);
    }
  }
  BARX();                                            // b1: all P0 reads done (lA, B0 free)
  stage32k(tfc1 + 16384,   B0, tid);                 // S3 (fc1 c1)
  if (lrow==0){
    #pragma unroll
    for (int r=0;r<4;r++){
      int row = wm + quad*4 + r;
      redS[half*64+row]=ps[r]; redQ[half*64+row]=pq[r];
    }
  }
  WAITL(); WAITV(8); BARX();                         // b2: red visible; S1 ready

  // ---- LN2 -> xn2 (c-major chunks, 64 rows) ----
  {
    float w2[4], b2[4];
    #pragma unroll
    for (int j=0;j<4;j++){ int col=wn+j*16+lrow; w2[j]=ln2w[col]; b2[j]=ln2b[col]; }
    #pragma unroll
    for (int r=0;r<4;r++){
      int row = wm + quad*4 + r;
      float mean = (redS[row]+redS[64+row])*0.0078125f;
      float var  = (redQ[row]+redQ[64+row])*0.0078125f - mean*mean;
      float rstd = rsqrtf(var + 1e-5f);
      #pragma unroll
      for (int j=0;j<4;j++){
        int col = wn + j*16 + lrow;
        ((u16*)xn2)[(row>>5)*4096 + ((col>>3)*32 + (row&31))*8 + (col&7)]
          = f2b((x1v[j][r]-mean)*rstd*w2[j] + b2[j]);
      }
    }
  }
  WAITL(); BARX();                                   // b3: xn2 visible

  f32x4 acc3[4] = {};

  // ---- P1: fc1 c0 (xn2, B1) -> gelu -> lA ----
  fc1_phase(xn2, B1, lA, bfc1, quad, lrow, wm, wn);
  WAITL(); BARX();                                   // b4: gelu visible; B1 free
  stage32k(tfc2 + 16384,   B1, tid);                 // S4 (fc2 c1)
  WAITV(8); BARX();                                  // b5: S2 ready

  // ---- P2: fc2 c0 (lA, B2) ----
  __builtin_amdgcn_s_setprio(1);
  mfma16(lA, B2, quad, lrow, wm, wn, acc3);
  __builtin_amdgcn_s_setprio(0);
  BARX();                                            // b6: lA, B2 free
  stage32k(tfc1 + 2*16384, B2, tid);                 // S5 (fc1 c2)
  WAITV(8); BARX();                                  // b7: S3 ready

  // ---- P3: fc1 c1 (xn2, B0) ----
  fc1_phase(xn2, B0, lA, bfc1 + 128, quad, lrow, wm, wn);
  WAITL(); BARX();                                   // b8: gelu visible; B0 free
  stage32k(tfc2 + 2*16384, B0, tid);                 // S6 (fc2 c2)
  WAITV(8); BARX();                                  // b9: S4 ready

  // ---- P4: fc2 c1 (lA, B1) ----
  __builtin_amdgcn_s_setprio(1);
  mfma16(lA, B1, quad, lrow, wm, wn, acc3);
  __builtin_amdgcn_s_setprio(0);
  BARX();                                            // b10: lA, B1 free
  stage32k(tfc1 + 3*16384, B1, tid);                 // S7 (fc1 c3)
  WAITV(8); BARX();                                  // b11: S5 ready

  // ---- P5: fc1 c2 (xn2, B2) ----
  fc1_phase(xn2, B2, lA, bfc1 + 256, quad, lrow, wm, wn);
  WAITL(); BARX();                                   // b12: gelu visible; B2 free
  stage32k(tfc2 + 3*16384, B2, tid);                 // S8 (fc2 c3)
  WAITV(8); BARX();                                  // b13: S6 ready

  // ---- P6: fc2 c2 (lA, B0) ----
  __builtin_amdgcn_s_setprio(1);
  mfma16(lA, B0, quad, lrow, wm, wn, acc3);
  __builtin_amdgcn_s_setprio(0);
  WAITV(4); BARX();                                  // b14: lA free + S7 ready

  // ---- P7: fc1 c3 (xn2, B1) ----
  fc1_phase(xn2, B1, lA, bfc1 + 384, quad, lrow, wm, wn);
  WAITL(); WAITV(0); BARX();                         // b15: gelu visible + S8 ready

  // ---- P8: fc2 c3 (lA, B2) ----
  __builtin_amdgcn_s_setprio(1);
  mfma16(lA, B2, quad, lrow, wm, wn, acc3);
  __builtin_amdgcn_s_setprio(0);

  // ---- epilogue: out = fc2 + bias + x1 ----
  #pragma unroll
  for (int j=0;j<4;j++){
    int col = wn + j*16 + lrow;
    float bia = bfc2[col];
    #pragma unroll
    for (int r=0;r<4;r++){
      int row = m0 + wm + quad*4 + r;
      out[(size_t)row*128 + col] = acc3[j][r] + bia + x1v[j][r];
    }
  }
}

extern "C" void kernel_launch(void* const* d_in, const int* in_sizes, int n_in,
                              void* d_out, int out_size, void* d_ws, size_t ws_size,
                              hipStream_t stream)
{
  const float* x     =(const float*)d_in[0];
  const float* ln1w  =(const float*)d_in[1];
  const float* ln1b  =(const float*)d_in[2];
  const float* wqkv  =(const float*)d_in[3];
  const float* bqkv  =(const float*)d_in[4];
  const float* rpb   =(const float*)d_in[5];
  const float* wproj =(const float*)d_in[6];
  const float* bproj =(const float*)d_in[7];
  const float* ln2w  =(const float*)d_in[8];
  const float* ln2b  =(const float*)d_in[9];
  const float* wfc1  =(const float*)d_in[10];
  const float* bfc1  =(const float*)d_in[11];
  const float* wfc2  =(const float*)d_in[12];
  const float* bfc2  =(const float*)d_in[13];

  char* ws=(char*)d_ws;
  size_t o=0;
  u16* tqkv =(u16*)(ws+o); o+=98304;
  u16* tproj=(u16*)(ws+o); o+=32768;
  u16* tfc1 =(u16*)(ws+o); o+=131072;
  u16* tfc2 =(u16*)(ws+o); o+=131072;
  u16* aout =(u16*)(ws+o); o+=3211264;
  u16* qb   =(u16*)(ws+o); o+=3211264;
  u16* kb   =(u16*)(ws+o); o+=3211264;
  u16* vb   =(u16*)(ws+o); o+=3211264;

  prep_kernel<<<768,256,0,stream>>>(wqkv,wproj,wfc1,wfc2,tqkv,tproj,tfc1,tfc2);
  qkv_ln_kernel<<<dim3(392,3),256,0,stream>>>(x,ln1w,ln1b,tqkv,bqkv,qb,kb,vb);
  attn_kernel<<<dim3(49,16),256,0,stream>>>(qb,kb,vb,rpb,aout);
  mega_mlp_kernel<<<196,512,0,stream>>>(aout,x,tproj,bproj,ln2w,ln2b,
                                        tfc1,bfc1,tfc2,bfc2,(float*)d_out);
}